// Round 12
// baseline (328.082 us; speedup 1.0000x reference)
//
#include <hip/hip_runtime.h>
#include <hip/hip_bf16.h>

#define B_ 4096
#define K_ 64
#define N_ 100000
#define E_ 128
#define T_ 3

typedef __bf16 bf16x8 __attribute__((ext_vector_type(8)));
typedef float  f32x4  __attribute__((ext_vector_type(4)));

static __device__ __forceinline__ bf16x8 cvt8r(f32x4 u, f32x4 v) {
    bf16x8 o;
    o[0] = (__bf16)u[0]; o[1] = (__bf16)u[1]; o[2] = (__bf16)u[2]; o[3] = (__bf16)u[3];
    o[4] = (__bf16)v[0]; o[5] = (__bf16)v[1]; o[6] = (__bf16)v[2]; o[7] = (__bf16)v[3];
    return o;
}

typedef const __attribute__((address_space(1))) void GAS;
typedef __attribute__((address_space(3))) void LAS;
static __device__ __forceinline__ void gload16(const void* g, void* l) {
    __builtin_amdgcn_global_load_lds((GAS*)g, (LAS*)l, 16, 0, 0);
}

#define MFMA16(a, b, c) __builtin_amdgcn_mfma_f32_16x16x32_bf16((a), (b), (c), 0, 0, 0)

// ---------------------------------------------------------------------------
// Kernel 0: transpose + bf16-convert weight matrices.
// ---------------------------------------------------------------------------
__global__ __launch_bounds__(256)
void k_prep(const float* __restrict__ W_f, const float* __restrict__ Wa1,
            const float* __restrict__ Wa2, const float* __restrict__ W1,
            __bf16* __restrict__ WtF, __bf16* __restrict__ Wa1t,
            __bf16* __restrict__ Wa2t, __bf16* __restrict__ W1t) {
    const int n = blockIdx.x;
    const int k = threadIdx.x;
    if (blockIdx.y == 0) {
        WtF[n * 256 + k] = (__bf16)W_f[k * 128 + n];
    } else if (blockIdx.y == 1) {
        if (k < 128) Wa1t[n * 128 + k] = (__bf16)Wa1[k * 128 + n];
    } else if (blockIdx.y == 2) {
        if (k < 128) Wa2t[n * 128 + k] = (__bf16)Wa2[k * 128 + n];
    } else {
        if (k < 128) W1t[n * 128 + k] = (__bf16)W1[k * 128 + n];
    }
}

// ---------------------------------------------------------------------------
// Kernel 1: nodes_fusion
// ---------------------------------------------------------------------------
__global__ __launch_bounds__(128)
void k_node_fusion(const int* __restrict__ nodes,
                   const float* __restrict__ node_emb,
                   const float* __restrict__ node_prof,
                   const float* __restrict__ W_f, const float* __restrict__ b_f,
                   __bf16* __restrict__ nodes_fusion) {
    __shared__ float x[256];
    const int b = blockIdx.x;
    const int e = threadIdx.x;
    const int nd = nodes[b];
    x[e]       = node_emb[(size_t)nd * E_ + e];
    x[128 + e] = node_prof[(size_t)nd * E_ + e];
    __syncthreads();
    float acc = b_f[e];
#pragma unroll 8
    for (int i = 0; i < 256; ++i) acc = fmaf(x[i], W_f[i * E_ + e], acc);
    nodes_fusion[(size_t)b * E_ + e] = (__bf16)fmaxf(acc, 0.f);
}

// ---------------------------------------------------------------------------
// Kernel 1b: node_pre (bf16 out)
// ---------------------------------------------------------------------------
__global__ __launch_bounds__(128)
void k_node_pre(const __bf16* __restrict__ nodes_fusion,
                const float* __restrict__ Wa1, const float* __restrict__ ba1,
                __bf16* __restrict__ node_pre) {
    __shared__ float x[128];
    const int b = blockIdx.x;
    const int c = threadIdx.x;
    x[c] = (float)nodes_fusion[(size_t)b * E_ + c];
    __syncthreads();
    float acc = ba1[c];
#pragma unroll 8
    for (int i = 0; i < 128; ++i) acc = fmaf(x[i], Wa1[(128 + i) * E_ + c], acc);
    node_pre[(size_t)b * E_ + c] = (__bf16)acc;
}

// ---------------------------------------------------------------------------
// Kernel NF v5: persistent pipelined precompute of NF *and* G = NF @ Wa1_top.
//   16-row tiles; DMA-staged X; W_f + Wa1 in VGPRs; counted vmcnt(2).
// ---------------------------------------------------------------------------
#define NF_GRID 768
#define NF_TPT (N_ / 16)
#define NF_NJOB (NF_TPT * T_)

__global__ __launch_bounds__(256, 3)
void k_nf(const float* __restrict__ neigh_emb,
          const float* __restrict__ neigh_prof,
          const __bf16* __restrict__ WtF, const float* __restrict__ b_f,
          const __bf16* __restrict__ Wa1t,
          __bf16* __restrict__ NFt, __bf16* __restrict__ Gt) {
    __shared__ __align__(16) float  Xf[2][16 * 256];   // 32 KB (G bounces in dead half)
    __shared__ __align__(16) __bf16 NFl[16 * 128];     // 4 KB

    const int tid  = threadIdx.x;
    const int wid  = tid >> 6, lane = tid & 63;
    const int lr   = lane & 15, lk = lane >> 4;

    // weights in registers (wave owns cols wid*32..+32)
    bf16x8 wf[16];
#pragma unroll
    for (int ks = 0; ks < 8; ++ks)
#pragma unroll
        for (int n = 0; n < 2; ++n)
            wf[ks * 2 + n] = *(const bf16x8*)&WtF[
                (size_t)(wid * 32 + n * 16 + lr) * 256 + ks * 32 + lk * 8];
    bf16x8 wa1r[8];
#pragma unroll
    for (int ks = 0; ks < 4; ++ks)
#pragma unroll
        for (int n = 0; n < 2; ++n)
            wa1r[ks * 2 + n] = *(const bf16x8*)&Wa1t[
                (size_t)(wid * 32 + n * 16 + lr) * 128 + ks * 32 + lk * 8];
    const float bb0 = b_f[wid * 32 + lr];
    const float bb1 = b_f[wid * 32 + 16 + lr];

    auto stage = [&](int j, int buf) {
        const int t    = j / NF_TPT;
        const int base = (j - t * NF_TPT) * 16;
        const float* embT  = neigh_emb  + (size_t)t * N_ * E_;
        const float* profT = neigh_prof + (size_t)t * N_ * E_;
#pragma unroll
        for (int i = 0; i < 4; ++i) {
            const int r  = wid * 4 + i;
            const int id = base + r;
            const int g  = lane ^ (r & 15);
            const float* src = (g < 32)
                ? embT  + (size_t)id * E_ + g * 4
                : profT + (size_t)id * E_ + (g - 32) * 4;
            gload16(src, (char*)&Xf[buf][0] + r * 1024);
        }
    };

    int job = blockIdx.x;
    stage(job, 0);
    int cur = 0;
    bool first = true;

    const int rr = tid >> 4, qq = tid & 15;        // store pattern
    const int pp = qq ^ rr;

    for (; job < NF_NJOB; job += NF_GRID) {
        const int tc    = job / NF_TPT;
        const int basec = (job - tc * NF_TPT) * 16;

        if (first) { asm volatile("s_waitcnt vmcnt(0)" ::: "memory"); first = false; }
        else       { asm volatile("s_waitcnt vmcnt(2)" ::: "memory"); }
        __builtin_amdgcn_s_barrier();
        __builtin_amdgcn_sched_barrier(0);

        const int nxt = job + NF_GRID;
        if (nxt < NF_NJOB) stage(nxt, cur ^ 1);

        const float* X = &Xf[cur][0];

        // ---- GEMM1: NF = relu(X @ W_f + b_f), K=256, 16 rows ----
        {
            f32x4 acc1[2] = {};
#pragma unroll
            for (int ks = 0; ks < 8; ++ks) {
                const int g0 = ks * 8 + lk * 2;
                const f32x4 u0 = *(const f32x4*)&X[lr * 256 + ((g0 ^ lr) << 2)];
                const f32x4 v0 = *(const f32x4*)&X[lr * 256 + (((g0 + 1) ^ lr) << 2)];
                const bf16x8 a0 = cvt8r(u0, v0);
                acc1[0] = MFMA16(a0, wf[ks * 2 + 0], acc1[0]);
                acc1[1] = MFMA16(a0, wf[ks * 2 + 1], acc1[1]);
            }
#pragma unroll
            for (int n = 0; n < 2; ++n) {
                const int c = wid * 32 + n * 16 + lr;
                const float bb = n ? bb1 : bb0;
                const int q = c >> 3, eo = c & 7;
#pragma unroll
                for (int j = 0; j < 4; ++j) {
                    const int rN = lk * 4 + j;
                    NFl[rN * 128 + ((q ^ rN) << 3) + eo] =
                        (__bf16)fmaxf(acc1[n][j] + bb, 0.f);
                }
            }
        }
        asm volatile("s_waitcnt lgkmcnt(0)" ::: "memory");
        __builtin_amdgcn_s_barrier();
        __builtin_amdgcn_sched_barrier(0);

        // ---- NF store (linear global layout) ----
        {
            __bf16* outp = NFt + ((size_t)tc * N_ + basec + rr) * E_ + qq * 8;
            *(bf16x8*)outp = *(const bf16x8*)&NFl[rr * 128 + (pp << 3)];
        }

        // ---- GEMM-G: G = NF @ Wa1_top (no bias, no relu) ----
        {
            f32x4 g[2] = {};
#pragma unroll
            for (int ks = 0; ks < 4; ++ks) {
                const int q = ks * 4 + lk;
                const bf16x8 a = *(const bf16x8*)&NFl[lr * 128 + ((q ^ lr) << 3)];
                g[0] = MFMA16(a, wa1r[ks * 2 + 0], g[0]);
                g[1] = MFMA16(a, wa1r[ks * 2 + 1], g[1]);
            }
            __bf16* Gl = (__bf16*)&Xf[cur][0];        // dead after GEMM1+barrier
#pragma unroll
            for (int n = 0; n < 2; ++n) {
                const int c = wid * 32 + n * 16 + lr;
                const int q = c >> 3, eo = c & 7;
#pragma unroll
                for (int j = 0; j < 4; ++j) {
                    const int rN = lk * 4 + j;
                    Gl[rN * 128 + ((q ^ rN) << 3) + eo] = (__bf16)g[n][j];
                }
            }
        }
        asm volatile("s_waitcnt lgkmcnt(0)" ::: "memory");
        __builtin_amdgcn_s_barrier();
        __builtin_amdgcn_sched_barrier(0);

        // ---- G store ----
        {
            const __bf16* Gl = (const __bf16*)&Xf[cur][0];
            __bf16* outp = Gt + ((size_t)tc * N_ + basec + rr) * E_ + qq * 8;
            *(bf16x8*)outp = *(const bf16x8*)&Gl[rr * 128 + (pp << 3)];
        }
        cur ^= 1;
    }
}

// ---------------------------------------------------------------------------
// Kernel ATT v6: persistent, 4 contiguous jobs/block (t block-uniform).
//   Gathers G (double-buffered, prefetch) + NF (single-buffered, wave-local,
//   lands during GEMM3+softmax). H1 = relu(G+npre) fused into A-fragments:
//   NO GEMM2, no H1 LDS round-trip. 32 MFMA/wave/job, 3 barriers/job.
//   Wave (mp,h): rows [32mp,+32) x cols [64h,+64). 3 blocks/CU (53.7 KB LDS).
// ---------------------------------------------------------------------------
#define ATT_JPB 4
#define ATT_GRID ((B_ * T_) / ATT_JPB)     /* 3072 */

__global__ __launch_bounds__(256, 3)
void k_att(const int* __restrict__ neigh_idx,
           const __bf16* __restrict__ NFt,
           const __bf16* __restrict__ Gt,
           const __bf16* __restrict__ Wa2t,
           const float* __restrict__ ba2,
           const float* __restrict__ Wa3, const float* __restrict__ ba3,
           const __bf16* __restrict__ node_pre,
           __bf16* __restrict__ aggB) {
    __shared__ __align__(16) __bf16 Gb[2][64 * 128];   // 32 KB
    __shared__ __align__(16) __bf16 Nb[64 * 128];      // 16 KB
    __shared__ int    idxL[ATT_JPB * 64];              // 1 KB
    __shared__ __bf16 npreL[ATT_JPB * 128];            // 1 KB
    __shared__ float  scp[128];                        // 0.5 KB
    __shared__ float  red4[512];                       // 2 KB

    const int tid = threadIdx.x;
    const int wid = tid >> 6, lane = tid & 63;
    const int lr = lane & 15, lk = lane >> 4;
    const int job0 = blockIdx.x * ATT_JPB;
    const int t    = job0 / B_;                        // uniform per block
    const int b0   = job0 % B_;

    const __bf16* NFtab = NFt + (size_t)t * N_ * E_;
    const __bf16* Gtab  = Gt  + (size_t)t * N_ * E_;

    // ---- weights for GEMM3: wave (mp,h) -> cols h*64 + n*16 + lr ----
    const int mp = wid >> 1, h = wid & 1;
    bf16x8 wa2r[4][4];
    float ba2r[4], wa3r[4];
#pragma unroll
    for (int n = 0; n < 4; ++n) {
        const int col = h * 64 + n * 16 + lr;
#pragma unroll
        for (int ks = 0; ks < 4; ++ks)
            wa2r[ks][n] = *(const bf16x8*)&Wa2t[(size_t)col * 128 + ks * 32 + lk * 8];
        ba2r[n] = ba2[col];
        wa3r[n] = Wa3[col];
    }
    const float ba3v = ba3[0];

    // ---- prologue: idx + npre for all 4 jobs into LDS ----
    idxL[tid] = neigh_idx[(size_t)job0 * K_ + tid];    // 256 = JPB*64 exactly
#pragma unroll
    for (int i = tid; i < ATT_JPB * 128; i += 256) {
        const int jj = i >> 7, c = i & 127;
        npreL[i] = node_pre[(size_t)(b0 + jj) * E_ + c];
    }
    __syncthreads();                                   // drains vmcnt too

    auto stage = [&](const __bf16* tab, int jj, char* dst) {
#pragma unroll
        for (int i = 0; i < 4; ++i) {
            const int rowblock = wid * 16 + i * 4;
            const int rsub = i * 4 + (lane >> 4);      // == row & 15
            const int q = (lane & 15) ^ rsub;
            const int id = idxL[jj * 64 + wid * 16 + rsub];
            gload16(tab + (size_t)id * E_ + q * 8, dst + rowblock * 256);
        }
    };

    stage(Gtab, 0, (char*)&Gb[0][0]);

    for (int it = 0; it < ATT_JPB; ++it) {
        // Gb[it] ready (leave last aggB store in flight)
        if (it == 0) { asm volatile("s_waitcnt vmcnt(0)" ::: "memory"); }
        else         { asm volatile("s_waitcnt vmcnt(1)" ::: "memory"); }
        __builtin_amdgcn_s_barrier();
        __builtin_amdgcn_sched_barrier(0);

        // issue N(it) then G(it+1): pre-agg vmcnt(4) drains N, keeps G flying
        stage(NFtab, it, (char*)&Nb[0]);
        if (it + 1 < ATT_JPB) stage(Gtab, it + 1, (char*)&Gb[(it + 1) & 1][0]);

        const __bf16* GbC = &Gb[it & 1][0];

        // ---- GEMM3: H2 = relu(H1 @ Wa2 + ba2); H1 = relu(G + npre) on the fly
        f32x4 acc[2][4] = {};
#pragma unroll
        for (int ks = 0; ks < 4; ++ks) {
            const int q = ks * 4 + lk;
            const bf16x8 g0 = *(const bf16x8*)&GbC[(32 * mp + lr) * 128 + ((q ^ lr) << 3)];
            const bf16x8 g1 = *(const bf16x8*)&GbC[(32 * mp + 16 + lr) * 128 + ((q ^ lr) << 3)];
            const bf16x8 np = *(const bf16x8*)&npreL[it * 128 + q * 8];
            bf16x8 a0, a1;
#pragma unroll
            for (int j = 0; j < 8; ++j) {
                const float nv = (float)np[j];
                a0[j] = (__bf16)fmaxf((float)g0[j] + nv, 0.f);
                a1[j] = (__bf16)fmaxf((float)g1[j] + nv, 0.f);
            }
#pragma unroll
            for (int n = 0; n < 4; ++n) {
                acc[0][n] = MFMA16(a0, wa2r[ks][n], acc[0][n]);
                acc[1][n] = MFMA16(a1, wa2r[ks][n], acc[1][n]);
            }
        }

        // ---- scores -> scp ----
#pragma unroll
        for (int mi = 0; mi < 2; ++mi)
#pragma unroll
            for (int j = 0; j < 4; ++j) {
                float v = 0.f;
#pragma unroll
                for (int n = 0; n < 4; ++n)
                    v += fmaxf(acc[mi][n][j] + ba2r[n], 0.f) * wa3r[n];
                v += __shfl_xor(v, 1);
                v += __shfl_xor(v, 2);
                v += __shfl_xor(v, 4);
                v += __shfl_xor(v, 8);
                if (lr == 0)
                    scp[h * 64 + 32 * mp + mi * 16 + lk * 4 + j] = v;
            }
        asm volatile("s_waitcnt lgkmcnt(0)" ::: "memory");
        __builtin_amdgcn_s_barrier();
        __builtin_amdgcn_sched_barrier(0);

        // ---- softmax over K=64, per wave (att in regs) ----
        float att;
        {
            const float v = scp[lane] + scp[64 + lane] + ba3v;
            float m = v;
#pragma unroll
            for (int o = 32; o > 0; o >>= 1) m = fmaxf(m, __shfl_xor(m, o));
            const float pe = __expf(v - m);
            float s = pe;
#pragma unroll
            for (int o = 32; o > 0; o >>= 1) s += __shfl_xor(s, o);
            att = pe / s;
        }

        // ---- N(it) landed (drains older store too; keeps G(it+1) flying) ----
        if (it + 1 < ATT_JPB) { asm volatile("s_waitcnt vmcnt(4)" ::: "memory"); }
        else                  { asm volatile("s_waitcnt vmcnt(0)" ::: "memory"); }
        __builtin_amdgcn_sched_barrier(0);

        // ---- agg over wave-local rows ----
        {
            float p0 = 0.f, p1 = 0.f;
            const int q0 = lane >> 3, eo = lane & 7;
            const int q1 = (lane + 64) >> 3;
#pragma unroll
            for (int i = 0; i < 16; ++i) {
                const int row = wid * 16 + i;
                const float av = __shfl(att, row);
                p0 = fmaf(av, (float)Nb[row * 128 + ((q0 ^ (row & 15)) << 3) + eo], p0);
                p1 = fmaf(av, (float)Nb[row * 128 + ((q1 ^ (row & 15)) << 3) + eo], p1);
            }
            red4[wid * 128 + lane] = p0;
            red4[wid * 128 + 64 + lane] = p1;
        }
        asm volatile("s_waitcnt lgkmcnt(0)" ::: "memory");
        __builtin_amdgcn_s_barrier();
        __builtin_amdgcn_sched_barrier(0);

        if (lane < 32) {
            const int e = wid * 32 + lane;
            const float s = red4[e] + red4[128 + e] + red4[256 + e] + red4[384 + e];
            aggB[((size_t)(b0 + it) * T_ + t) * E_ + e] = (__bf16)s;
        }
    }
}

// ---------------------------------------------------------------------------
// Kernel 2b: type_agg = relu(aggB @ W1 + b1), M=B*T=12288, K=N=128.
// ---------------------------------------------------------------------------
__global__ __launch_bounds__(256)
void k_w1(const __bf16* __restrict__ aggB, const __bf16* __restrict__ W1t,
          const float* __restrict__ b1, __bf16* __restrict__ type_agg) {
    const int tid  = threadIdx.x;
    const int wid  = tid >> 6;
    const int lane = tid & 63;
    const int lr   = lane & 15;
    const int lk   = lane >> 4;
    const int rbase = blockIdx.x * 64 + wid * 16;

    f32x4 acc[8] = {};
#pragma unroll
    for (int ks = 0; ks < 4; ++ks) {
        const bf16x8 a = *(const bf16x8*)&aggB[(size_t)(rbase + lr) * 128 + ks * 32 + lk * 8];
        const __bf16* wb = W1t + (size_t)lr * 128 + ks * 32 + lk * 8;
#pragma unroll
        for (int n = 0; n < 8; ++n) {
            const bf16x8 w = *(const bf16x8*)(wb + (size_t)n * 16 * 128);
            acc[n] = MFMA16(a, w, acc[n]);
        }
    }
#pragma unroll
    for (int n = 0; n < 8; ++n) {
        const int col = n * 16 + lr;
        const float bb = b1[col];
#pragma unroll
        for (int j = 0; j < 4; ++j) {
            const int row = rbase + lk * 4 + j;
            type_agg[(size_t)row * 128 + col] = (__bf16)fmaxf(acc[n][j] + bb, 0.f);
        }
    }
}

// ---------------------------------------------------------------------------
// Kernel 3: type softmax + final MLP + output head.
// ---------------------------------------------------------------------------
__global__ __launch_bounds__(128)
void k_final(const __bf16* __restrict__ type_agg,
             const __bf16* __restrict__ nodes_fusion,
             const float* __restrict__ Wt,
             const float* __restrict__ W2, const float* __restrict__ b2,
             const float* __restrict__ Wc, const float* __restrict__ bc,
             float* __restrict__ out, float* __restrict__ att_out) {
    __shared__ float ta[384];
    __shared__ float nfu[128];
    __shared__ float fin[128];
    __shared__ float hb[128];
    __shared__ float att[3];
    __shared__ float red[3][128];

    const int b = blockIdx.x;
    const int e = threadIdx.x;

    const float v0 = (float)type_agg[(size_t)b * 384 + e];
    const float v1 = (float)type_agg[(size_t)b * 384 + 128 + e];
    const float v2 = (float)type_agg[(size_t)b * 384 + 256 + e];
    ta[e] = v0; ta[128 + e] = v1; ta[256 + e] = v2;
    nfu[e] = (float)nodes_fusion[(size_t)b * E_ + e];

    float p0, p1, p2;
    {
        const float* w0 = Wt + (size_t)e * 3;
        const float* w1 = Wt + (size_t)(128 + e) * 3;
        const float* w2 = Wt + (size_t)(256 + e) * 3;
        p0 = v0 * w0[0] + v1 * w1[0] + v2 * w2[0];
        p1 = v0 * w0[1] + v1 * w1[1] + v2 * w2[1];
        p2 = v0 * w0[2] + v1 * w1[2] + v2 * w2[2];
    }
    red[0][e] = p0; red[1][e] = p1; red[2][e] = p2;
    __syncthreads();

    if (e < 3) {
        float s = 0.f;
        for (int i = 0; i < 128; ++i) s += red[e][i];
        red[e][0] = s;
    }
    __syncthreads();
    if (e == 0) {
        const float s0 = red[0][0], s1 = red[1][0], s2 = red[2][0];
        const float m  = fmaxf(s0, fmaxf(s1, s2));
        const float e0 = __expf(s0 - m), e1 = __expf(s1 - m), e2 = __expf(s2 - m);
        const float inv = 1.f / (e0 + e1 + e2);
        att[0] = e0 * inv; att[1] = e1 * inv; att[2] = e2 * inv;
    }
    __syncthreads();

    fin[e] = att[0] * ta[e] + att[1] * ta[128 + e] + att[2] * ta[256 + e];
    __syncthreads();

    float acc = b2[e];
#pragma unroll 8
    for (int i = 0; i < 128; ++i) acc = fmaf(fin[i], W2[i * E_ + e], acc);
    hb[e] = fmaxf(acc, 0.f);
    __syncthreads();

    float acc2 = bc[e];
#pragma unroll 8
    for (int i = 0; i < 128; ++i) acc2 = fmaf(nfu[i], Wc[i * E_ + e], acc2);
#pragma unroll 8
    for (int i = 0; i < 128; ++i) acc2 = fmaf(hb[i], Wc[(128 + i) * E_ + e], acc2);
    out[(size_t)b * E_ + e] = fmaxf(acc2, 0.f);

    if (e < 3) att_out[(size_t)b * 3 + e] = att[e];
}

// ---------------------------------------------------------------------------
extern "C" void kernel_launch(void* const* d_in, const int* in_sizes, int n_in,
                              void* d_out, int out_size, void* d_ws, size_t ws_size,
                              hipStream_t stream) {
    const int*   nodes      = (const int*)d_in[0];
    const int*   neigh_idx  = (const int*)d_in[1];
    const float* node_emb   = (const float*)d_in[2];
    const float* node_prof  = (const float*)d_in[3];
    const float* neigh_emb  = (const float*)d_in[4];
    const float* neigh_prof = (const float*)d_in[5];
    const float* W_f = (const float*)d_in[6];  const float* b_f = (const float*)d_in[7];
    const float* Wa1 = (const float*)d_in[8];  const float* ba1 = (const float*)d_in[9];
    const float* Wa2 = (const float*)d_in[10]; const float* ba2 = (const float*)d_in[11];
    const float* Wa3 = (const float*)d_in[12]; const float* ba3 = (const float*)d_in[13];
    const float* W1  = (const float*)d_in[14]; const float* b1  = (const float*)d_in[15];
    const float* W2  = (const float*)d_in[16]; const float* b2  = (const float*)d_in[17];
    const float* Wc  = (const float*)d_in[18]; const float* bc  = (const float*)d_in[19];
    const float* Wt  = (const float*)d_in[20];

    float* out     = (float*)d_out;
    float* att_out = out + (size_t)B_ * E_;

    char* ws = (char*)d_ws;
    __bf16* nodes_fusion = (__bf16*)(ws);                       // 1 MB @ 0
    __bf16* node_pre     = (__bf16*)(ws + (1u << 20));          // 1 MB @ 1M
    __bf16* type_agg     = (__bf16*)(ws + (2u << 20));          // 3 MB @ 2M
    __bf16* aggB         = (__bf16*)(ws + (5u << 20));          // 3 MB @ 5M
    __bf16* WtF          = (__bf16*)(ws + (8u << 20));          // 64 KB
    __bf16* Wa1t         = (__bf16*)(ws + (8u << 20) + 65536);
    __bf16* Wa2t         = (__bf16*)(ws + (8u << 20) + 98304);
    __bf16* W1t          = (__bf16*)(ws + (8u << 20) + 131072);
    __bf16* NFt          = (__bf16*)(ws + (9u << 20));          // 73.3 MiB @ 9M
    __bf16* Gt           = (__bf16*)(ws + (83u << 20));         // 73.3 MiB @ 83M

    k_prep<<<dim3(128, 4), 256, 0, stream>>>(W_f, Wa1, Wa2, W1, WtF, Wa1t, Wa2t, W1t);
    k_node_fusion<<<B_, 128, 0, stream>>>(nodes, node_emb, node_prof, W_f, b_f,
                                          nodes_fusion);
    k_node_pre<<<B_, 128, 0, stream>>>(nodes_fusion, Wa1, ba1, node_pre);
    k_nf<<<NF_GRID, 256, 0, stream>>>(neigh_emb, neigh_prof, WtF, b_f, Wa1t,
                                      NFt, Gt);
    k_att<<<ATT_GRID, 256, 0, stream>>>(neigh_idx, NFt, Gt, Wa2t, ba2,
                                        Wa3, ba3, node_pre, aggB);
    k_w1<<<(B_ * T_) / 64, 256, 0, stream>>>(aggB, W1t, b1, type_agg);
    k_final<<<B_, 128, 0, stream>>>(type_agg, nodes_fusion, Wt, W2, b2, Wc, bc,
                                    out, att_out);
}

// Round 13
// 302.810 us; speedup vs baseline: 1.0835x; 1.0835x over previous
//
#include <hip/hip_runtime.h>
#include <hip/hip_bf16.h>

#define B_ 4096
#define K_ 64
#define N_ 100000
#define E_ 128
#define T_ 3

typedef __bf16 bf16x8 __attribute__((ext_vector_type(8)));
typedef float  f32x4  __attribute__((ext_vector_type(4)));

static __device__ __forceinline__ bf16x8 cvt8r(f32x4 u, f32x4 v) {
    bf16x8 o;
    o[0] = (__bf16)u[0]; o[1] = (__bf16)u[1]; o[2] = (__bf16)u[2]; o[3] = (__bf16)u[3];
    o[4] = (__bf16)v[0]; o[5] = (__bf16)v[1]; o[6] = (__bf16)v[2]; o[7] = (__bf16)v[3];
    return o;
}

typedef const __attribute__((address_space(1))) void GAS;
typedef __attribute__((address_space(3))) void LAS;
static __device__ __forceinline__ void gload16(const void* g, void* l) {
    __builtin_amdgcn_global_load_lds((GAS*)g, (LAS*)l, 16, 0, 0);
}

#define MFMA16(a, b, c) __builtin_amdgcn_mfma_f32_16x16x32_bf16((a), (b), (c), 0, 0, 0)

// ---------------------------------------------------------------------------
// Kernel 0: transpose + bf16-convert weight matrices.
// ---------------------------------------------------------------------------
__global__ __launch_bounds__(256)
void k_prep(const float* __restrict__ W_f, const float* __restrict__ Wa1,
            const float* __restrict__ Wa2, const float* __restrict__ W1,
            __bf16* __restrict__ WtF, __bf16* __restrict__ Wa1t,
            __bf16* __restrict__ Wa2t, __bf16* __restrict__ W1t) {
    const int n = blockIdx.x;
    const int k = threadIdx.x;
    if (blockIdx.y == 0) {
        WtF[n * 256 + k] = (__bf16)W_f[k * 128 + n];
    } else if (blockIdx.y == 1) {
        if (k < 128) Wa1t[n * 128 + k] = (__bf16)Wa1[k * 128 + n];
    } else if (blockIdx.y == 2) {
        if (k < 128) Wa2t[n * 128 + k] = (__bf16)Wa2[k * 128 + n];
    } else {
        if (k < 128) W1t[n * 128 + k] = (__bf16)W1[k * 128 + n];
    }
}

// ---------------------------------------------------------------------------
// Kernel 1: nodes_fusion
// ---------------------------------------------------------------------------
__global__ __launch_bounds__(128)
void k_node_fusion(const int* __restrict__ nodes,
                   const float* __restrict__ node_emb,
                   const float* __restrict__ node_prof,
                   const float* __restrict__ W_f, const float* __restrict__ b_f,
                   __bf16* __restrict__ nodes_fusion) {
    __shared__ float x[256];
    const int b = blockIdx.x;
    const int e = threadIdx.x;
    const int nd = nodes[b];
    x[e]       = node_emb[(size_t)nd * E_ + e];
    x[128 + e] = node_prof[(size_t)nd * E_ + e];
    __syncthreads();
    float acc = b_f[e];
#pragma unroll 8
    for (int i = 0; i < 256; ++i) acc = fmaf(x[i], W_f[i * E_ + e], acc);
    nodes_fusion[(size_t)b * E_ + e] = (__bf16)fmaxf(acc, 0.f);
}

// ---------------------------------------------------------------------------
// Kernel 1b: node_pre (bf16 out)
// ---------------------------------------------------------------------------
__global__ __launch_bounds__(128)
void k_node_pre(const __bf16* __restrict__ nodes_fusion,
                const float* __restrict__ Wa1, const float* __restrict__ ba1,
                __bf16* __restrict__ node_pre) {
    __shared__ float x[128];
    const int b = blockIdx.x;
    const int c = threadIdx.x;
    x[c] = (float)nodes_fusion[(size_t)b * E_ + c];
    __syncthreads();
    float acc = ba1[c];
#pragma unroll 8
    for (int i = 0; i < 128; ++i) acc = fmaf(x[i], Wa1[(128 + i) * E_ + c], acc);
    node_pre[(size_t)b * E_ + c] = (__bf16)acc;
}

// ---------------------------------------------------------------------------
// Kernel NF v5 (unchanged from round 12): NF + G = NF @ Wa1_top tables.
// ---------------------------------------------------------------------------
#define NF_GRID 768
#define NF_TPT (N_ / 16)
#define NF_NJOB (NF_TPT * T_)

__global__ __launch_bounds__(256, 3)
void k_nf(const float* __restrict__ neigh_emb,
          const float* __restrict__ neigh_prof,
          const __bf16* __restrict__ WtF, const float* __restrict__ b_f,
          const __bf16* __restrict__ Wa1t,
          __bf16* __restrict__ NFt, __bf16* __restrict__ Gt) {
    __shared__ __align__(16) float  Xf[2][16 * 256];
    __shared__ __align__(16) __bf16 NFl[16 * 128];

    const int tid  = threadIdx.x;
    const int wid  = tid >> 6, lane = tid & 63;
    const int lr   = lane & 15, lk = lane >> 4;

    bf16x8 wf[16];
#pragma unroll
    for (int ks = 0; ks < 8; ++ks)
#pragma unroll
        for (int n = 0; n < 2; ++n)
            wf[ks * 2 + n] = *(const bf16x8*)&WtF[
                (size_t)(wid * 32 + n * 16 + lr) * 256 + ks * 32 + lk * 8];
    bf16x8 wa1r[8];
#pragma unroll
    for (int ks = 0; ks < 4; ++ks)
#pragma unroll
        for (int n = 0; n < 2; ++n)
            wa1r[ks * 2 + n] = *(const bf16x8*)&Wa1t[
                (size_t)(wid * 32 + n * 16 + lr) * 128 + ks * 32 + lk * 8];
    const float bb0 = b_f[wid * 32 + lr];
    const float bb1 = b_f[wid * 32 + 16 + lr];

    auto stage = [&](int j, int buf) {
        const int t    = j / NF_TPT;
        const int base = (j - t * NF_TPT) * 16;
        const float* embT  = neigh_emb  + (size_t)t * N_ * E_;
        const float* profT = neigh_prof + (size_t)t * N_ * E_;
#pragma unroll
        for (int i = 0; i < 4; ++i) {
            const int r  = wid * 4 + i;
            const int id = base + r;
            const int g  = lane ^ (r & 15);
            const float* src = (g < 32)
                ? embT  + (size_t)id * E_ + g * 4
                : profT + (size_t)id * E_ + (g - 32) * 4;
            gload16(src, (char*)&Xf[buf][0] + r * 1024);
        }
    };

    int job = blockIdx.x;
    stage(job, 0);
    int cur = 0;
    bool first = true;

    const int rr = tid >> 4, qq = tid & 15;
    const int pp = qq ^ rr;

    for (; job < NF_NJOB; job += NF_GRID) {
        const int tc    = job / NF_TPT;
        const int basec = (job - tc * NF_TPT) * 16;

        if (first) { asm volatile("s_waitcnt vmcnt(0)" ::: "memory"); first = false; }
        else       { asm volatile("s_waitcnt vmcnt(2)" ::: "memory"); }
        __builtin_amdgcn_s_barrier();
        __builtin_amdgcn_sched_barrier(0);

        const int nxt = job + NF_GRID;
        if (nxt < NF_NJOB) stage(nxt, cur ^ 1);

        const float* X = &Xf[cur][0];

        {
            f32x4 acc1[2] = {};
#pragma unroll
            for (int ks = 0; ks < 8; ++ks) {
                const int g0 = ks * 8 + lk * 2;
                const f32x4 u0 = *(const f32x4*)&X[lr * 256 + ((g0 ^ lr) << 2)];
                const f32x4 v0 = *(const f32x4*)&X[lr * 256 + (((g0 + 1) ^ lr) << 2)];
                const bf16x8 a0 = cvt8r(u0, v0);
                acc1[0] = MFMA16(a0, wf[ks * 2 + 0], acc1[0]);
                acc1[1] = MFMA16(a0, wf[ks * 2 + 1], acc1[1]);
            }
#pragma unroll
            for (int n = 0; n < 2; ++n) {
                const int c = wid * 32 + n * 16 + lr;
                const float bb = n ? bb1 : bb0;
                const int q = c >> 3, eo = c & 7;
#pragma unroll
                for (int j = 0; j < 4; ++j) {
                    const int rN = lk * 4 + j;
                    NFl[rN * 128 + ((q ^ rN) << 3) + eo] =
                        (__bf16)fmaxf(acc1[n][j] + bb, 0.f);
                }
            }
        }
        asm volatile("s_waitcnt lgkmcnt(0)" ::: "memory");
        __builtin_amdgcn_s_barrier();
        __builtin_amdgcn_sched_barrier(0);

        {
            __bf16* outp = NFt + ((size_t)tc * N_ + basec + rr) * E_ + qq * 8;
            *(bf16x8*)outp = *(const bf16x8*)&NFl[rr * 128 + (pp << 3)];
        }

        {
            f32x4 g[2] = {};
#pragma unroll
            for (int ks = 0; ks < 4; ++ks) {
                const int q = ks * 4 + lk;
                const bf16x8 a = *(const bf16x8*)&NFl[lr * 128 + ((q ^ lr) << 3)];
                g[0] = MFMA16(a, wa1r[ks * 2 + 0], g[0]);
                g[1] = MFMA16(a, wa1r[ks * 2 + 1], g[1]);
            }
            __bf16* Gl = (__bf16*)&Xf[cur][0];
#pragma unroll
            for (int n = 0; n < 2; ++n) {
                const int c = wid * 32 + n * 16 + lr;
                const int q = c >> 3, eo = c & 7;
#pragma unroll
                for (int j = 0; j < 4; ++j) {
                    const int rN = lk * 4 + j;
                    Gl[rN * 128 + ((q ^ rN) << 3) + eo] = (__bf16)g[n][j];
                }
            }
        }
        asm volatile("s_waitcnt lgkmcnt(0)" ::: "memory");
        __builtin_amdgcn_s_barrier();
        __builtin_amdgcn_sched_barrier(0);

        {
            const __bf16* Gl = (const __bf16*)&Xf[cur][0];
            __bf16* outp = Gt + ((size_t)tc * N_ + basec + rr) * E_ + qq * 8;
            *(bf16x8*)outp = *(const bf16x8*)&Gl[rr * 128 + (pp << 3)];
        }
        cur ^= 1;
    }
}

// ---------------------------------------------------------------------------
// Kernel ATT v7: non-persistent, one (b,t) job per block, TWO barriers.
//   Rationale (r10-r12 post-mortems): per-job barrier structure, not gather
//   latency or MFMA count, pins k_att at ~160 µs. Max independent blocks
//   (4/CU, 16 waves) + min barriers. Wa2 read in-loop from global (L1-hit,
//   harmless without a DMA pipeline to protect). Redundant per-wave softmax;
//   wave-local agg (wave wid -> elems [32wid,+32) over all 64 rows) kills
//   the red4 reduction barrier.
// ---------------------------------------------------------------------------
__global__ __launch_bounds__(256, 4)
void k_att(const int* __restrict__ neigh_idx,
           const __bf16* __restrict__ NFt,
           const __bf16* __restrict__ Gt,
           const __bf16* __restrict__ Wa2t,
           const float* __restrict__ ba2,
           const float* __restrict__ Wa3, const float* __restrict__ ba3,
           const __bf16* __restrict__ node_pre,
           __bf16* __restrict__ aggB) {
    __shared__ __align__(16) __bf16 Gb[64 * 128];   // 16 KB
    __shared__ __align__(16) __bf16 Nb[64 * 128];   // 16 KB
    __shared__ __bf16 npreL[128];                   // 256 B
    __shared__ float  scp[128];                     // 512 B

    const int b   = blockIdx.x;
    const int t   = blockIdx.y;
    const int tid = threadIdx.x;
    const int wid = tid >> 6, lane = tid & 63;
    const int lr = lane & 15, lk = lane >> 4;

    // per-wave row ids in registers (lane L holds id of row wid*16 + (L&15))
    const int idv = neigh_idx[((size_t)t * B_ + b) * K_ + wid * 16 + lr];

    const __bf16* Gtab  = Gt  + (size_t)t * N_ * E_;
    const __bf16* NFtab = NFt + (size_t)t * N_ * E_;
#pragma unroll
    for (int i = 0; i < 4; ++i) {
        const int rowblock = wid * 16 + i * 4;
        const int rsub = i * 4 + (lane >> 4);          // == row & 15
        const int q = (lane & 15) ^ rsub;              // source pre-swizzle
        const int id = __shfl(idv, rsub);
        gload16(Gtab  + (size_t)id * E_ + q * 8, (char*)Gb + rowblock * 256);
        gload16(NFtab + (size_t)id * E_ + q * 8, (char*)Nb + rowblock * 256);
    }
    if (tid < 128) npreL[tid] = node_pre[(size_t)b * E_ + tid];
    __syncthreads();                                   // barrier 1 (drains DMA)

    // ---- GEMM3: H2 = relu(H1 @ Wa2 + ba2); H1 = relu(G + npre) on the fly
    const int mp = wid >> 1, h = wid & 1;              // rows 32mp..+32, cols 64h..+64
    f32x4 acc[2][4] = {};
#pragma unroll
    for (int ks = 0; ks < 4; ++ks) {
        const int q = ks * 4 + lk;
        const bf16x8 g0 = *(const bf16x8*)&Gb[(32 * mp + lr) * 128 + ((q ^ lr) << 3)];
        const bf16x8 g1 = *(const bf16x8*)&Gb[(32 * mp + 16 + lr) * 128 + ((q ^ lr) << 3)];
        const bf16x8 np = *(const bf16x8*)&npreL[q * 8];
        bf16x8 a0, a1;
#pragma unroll
        for (int j = 0; j < 8; ++j) {
            const float nv = (float)np[j];
            a0[j] = (__bf16)fmaxf((float)g0[j] + nv, 0.f);
            a1[j] = (__bf16)fmaxf((float)g1[j] + nv, 0.f);
        }
        const __bf16* wb = Wa2t + (size_t)(h * 64 + lr) * 128 + ks * 32 + lk * 8;
#pragma unroll
        for (int n = 0; n < 4; ++n) {
            const bf16x8 w = *(const bf16x8*)(wb + (size_t)n * 16 * 128);
            acc[0][n] = MFMA16(a0, w, acc[0][n]);
            acc[1][n] = MFMA16(a1, w, acc[1][n]);
        }
    }

    // ---- scores -> scp (partial over this wave's 64-col half) ----
    {
        float ba2r[4], wa3r[4];
#pragma unroll
        for (int n = 0; n < 4; ++n) {
            const int col = h * 64 + n * 16 + lr;
            ba2r[n] = ba2[col];
            wa3r[n] = Wa3[col];
        }
#pragma unroll
        for (int mi = 0; mi < 2; ++mi)
#pragma unroll
            for (int j = 0; j < 4; ++j) {
                float v = 0.f;
#pragma unroll
                for (int n = 0; n < 4; ++n)
                    v += fmaxf(acc[mi][n][j] + ba2r[n], 0.f) * wa3r[n];
                v += __shfl_xor(v, 1);
                v += __shfl_xor(v, 2);
                v += __shfl_xor(v, 4);
                v += __shfl_xor(v, 8);
                if (lr == 0)
                    scp[h * 64 + 32 * mp + mi * 16 + lk * 4 + j] = v;
            }
    }
    __syncthreads();                                   // barrier 2

    // ---- softmax over K=64, redundantly per wave (lane holds att[lane]) ----
    float att;
    {
        const float v = scp[lane] + scp[64 + lane] + ba3[0];
        float m = v;
#pragma unroll
        for (int o = 32; o > 0; o >>= 1) m = fmaxf(m, __shfl_xor(m, o));
        const float pe = __expf(v - m);
        float s = pe;
#pragma unroll
        for (int o = 32; o > 0; o >>= 1) s += __shfl_xor(s, o);
        att = pe / s;
    }

    // ---- wave-local agg: wave wid -> elems [32wid,+32), all 64 rows ----
    {
        const int e = wid * 32 + (lane & 31);
        const int half = lane >> 5;                    // rows half*32..+32
        const int qe = e >> 3, eo = e & 7;
        float p = 0.f;
#pragma unroll
        for (int i = 0; i < 32; ++i) {
            const int row = half * 32 + i;
            const float av = __shfl(att, row);
            p = fmaf(av, (float)Nb[row * 128 + ((qe ^ (row & 15)) << 3) + eo], p);
        }
        p += __shfl_xor(p, 32);
        if (lane < 32)
            aggB[((size_t)b * T_ + t) * E_ + e] = (__bf16)p;
    }
}

// ---------------------------------------------------------------------------
// Kernel 2b: type_agg = relu(aggB @ W1 + b1), M=B*T=12288, K=N=128.
// ---------------------------------------------------------------------------
__global__ __launch_bounds__(256)
void k_w1(const __bf16* __restrict__ aggB, const __bf16* __restrict__ W1t,
          const float* __restrict__ b1, __bf16* __restrict__ type_agg) {
    const int tid  = threadIdx.x;
    const int wid  = tid >> 6;
    const int lane = tid & 63;
    const int lr   = lane & 15;
    const int lk   = lane >> 4;
    const int rbase = blockIdx.x * 64 + wid * 16;

    f32x4 acc[8] = {};
#pragma unroll
    for (int ks = 0; ks < 4; ++ks) {
        const bf16x8 a = *(const bf16x8*)&aggB[(size_t)(rbase + lr) * 128 + ks * 32 + lk * 8];
        const __bf16* wb = W1t + (size_t)lr * 128 + ks * 32 + lk * 8;
#pragma unroll
        for (int n = 0; n < 8; ++n) {
            const bf16x8 w = *(const bf16x8*)(wb + (size_t)n * 16 * 128);
            acc[n] = MFMA16(a, w, acc[n]);
        }
    }
#pragma unroll
    for (int n = 0; n < 8; ++n) {
        const int col = n * 16 + lr;
        const float bb = b1[col];
#pragma unroll
        for (int j = 0; j < 4; ++j) {
            const int row = rbase + lk * 4 + j;
            type_agg[(size_t)row * 128 + col] = (__bf16)fmaxf(acc[n][j] + bb, 0.f);
        }
    }
}

// ---------------------------------------------------------------------------
// Kernel 3: type softmax + final MLP + output head.
// ---------------------------------------------------------------------------
__global__ __launch_bounds__(128)
void k_final(const __bf16* __restrict__ type_agg,
             const __bf16* __restrict__ nodes_fusion,
             const float* __restrict__ Wt,
             const float* __restrict__ W2, const float* __restrict__ b2,
             const float* __restrict__ Wc, const float* __restrict__ bc,
             float* __restrict__ out, float* __restrict__ att_out) {
    __shared__ float ta[384];
    __shared__ float nfu[128];
    __shared__ float fin[128];
    __shared__ float hb[128];
    __shared__ float att[3];
    __shared__ float red[3][128];

    const int b = blockIdx.x;
    const int e = threadIdx.x;

    const float v0 = (float)type_agg[(size_t)b * 384 + e];
    const float v1 = (float)type_agg[(size_t)b * 384 + 128 + e];
    const float v2 = (float)type_agg[(size_t)b * 384 + 256 + e];
    ta[e] = v0; ta[128 + e] = v1; ta[256 + e] = v2;
    nfu[e] = (float)nodes_fusion[(size_t)b * E_ + e];

    float p0, p1, p2;
    {
        const float* w0 = Wt + (size_t)e * 3;
        const float* w1 = Wt + (size_t)(128 + e) * 3;
        const float* w2 = Wt + (size_t)(256 + e) * 3;
        p0 = v0 * w0[0] + v1 * w1[0] + v2 * w2[0];
        p1 = v0 * w0[1] + v1 * w1[1] + v2 * w2[1];
        p2 = v0 * w0[2] + v1 * w1[2] + v2 * w2[2];
    }
    red[0][e] = p0; red[1][e] = p1; red[2][e] = p2;
    __syncthreads();

    if (e < 3) {
        float s = 0.f;
        for (int i = 0; i < 128; ++i) s += red[e][i];
        red[e][0] = s;
    }
    __syncthreads();
    if (e == 0) {
        const float s0 = red[0][0], s1 = red[1][0], s2 = red[2][0];
        const float m  = fmaxf(s0, fmaxf(s1, s2));
        const float e0 = __expf(s0 - m), e1 = __expf(s1 - m), e2 = __expf(s2 - m);
        const float inv = 1.f / (e0 + e1 + e2);
        att[0] = e0 * inv; att[1] = e1 * inv; att[2] = e2 * inv;
    }
    __syncthreads();

    fin[e] = att[0] * ta[e] + att[1] * ta[128 + e] + att[2] * ta[256 + e];
    __syncthreads();

    float acc = b2[e];
#pragma unroll 8
    for (int i = 0; i < 128; ++i) acc = fmaf(fin[i], W2[i * E_ + e], acc);
    hb[e] = fmaxf(acc, 0.f);
    __syncthreads();

    float acc2 = bc[e];
#pragma unroll 8
    for (int i = 0; i < 128; ++i) acc2 = fmaf(nfu[i], Wc[i * E_ + e], acc2);
#pragma unroll 8
    for (int i = 0; i < 128; ++i) acc2 = fmaf(hb[i], Wc[(128 + i) * E_ + e], acc2);
    out[(size_t)b * E_ + e] = fmaxf(acc2, 0.f);

    if (e < 3) att_out[(size_t)b * 3 + e] = att[e];
}

// ---------------------------------------------------------------------------
extern "C" void kernel_launch(void* const* d_in, const int* in_sizes, int n_in,
                              void* d_out, int out_size, void* d_ws, size_t ws_size,
                              hipStream_t stream) {
    const int*   nodes      = (const int*)d_in[0];
    const int*   neigh_idx  = (const int*)d_in[1];
    const float* node_emb   = (const float*)d_in[2];
    const float* node_prof  = (const float*)d_in[3];
    const float* neigh_emb  = (const float*)d_in[4];
    const float* neigh_prof = (const float*)d_in[5];
    const float* W_f = (const float*)d_in[6];  const float* b_f = (const float*)d_in[7];
    const float* Wa1 = (const float*)d_in[8];  const float* ba1 = (const float*)d_in[9];
    const float* Wa2 = (const float*)d_in[10]; const float* ba2 = (const float*)d_in[11];
    const float* Wa3 = (const float*)d_in[12]; const float* ba3 = (const float*)d_in[13];
    const float* W1  = (const float*)d_in[14]; const float* b1  = (const float*)d_in[15];
    const float* W2  = (const float*)d_in[16]; const float* b2  = (const float*)d_in[17];
    const float* Wc  = (const float*)d_in[18]; const float* bc  = (const float*)d_in[19];
    const float* Wt  = (const float*)d_in[20];

    float* out     = (float*)d_out;
    float* att_out = out + (size_t)B_ * E_;

    char* ws = (char*)d_ws;
    __bf16* nodes_fusion = (__bf16*)(ws);                       // 1 MB @ 0
    __bf16* node_pre     = (__bf16*)(ws + (1u << 20));          // 1 MB @ 1M
    __bf16* type_agg     = (__bf16*)(ws + (2u << 20));          // 3 MB @ 2M
    __bf16* aggB         = (__bf16*)(ws + (5u << 20));          // 3 MB @ 5M
    __bf16* WtF          = (__bf16*)(ws + (8u << 20));          // 64 KB
    __bf16* Wa1t         = (__bf16*)(ws + (8u << 20) + 65536);
    __bf16* Wa2t         = (__bf16*)(ws + (8u << 20) + 98304);
    __bf16* W1t          = (__bf16*)(ws + (8u << 20) + 131072);
    __bf16* NFt          = (__bf16*)(ws + (9u << 20));          // 73.3 MiB @ 9M
    __bf16* Gt           = (__bf16*)(ws + (83u << 20));         // 73.3 MiB @ 83M

    k_prep<<<dim3(128, 4), 256, 0, stream>>>(W_f, Wa1, Wa2, W1, WtF, Wa1t, Wa2t, W1t);
    k_node_fusion<<<B_, 128, 0, stream>>>(nodes, node_emb, node_prof, W_f, b_f,
                                          nodes_fusion);
    k_node_pre<<<B_, 128, 0, stream>>>(nodes_fusion, Wa1, ba1, node_pre);
    k_nf<<<NF_GRID, 256, 0, stream>>>(neigh_emb, neigh_prof, WtF, b_f, Wa1t,
                                      NFt, Gt);
    k_att<<<dim3(B_, T_), 256, 0, stream>>>(neigh_idx, NFt, Gt, Wa2t, ba2,
                                            Wa3, ba3, node_pre, aggB);
    k_w1<<<(B_ * T_) / 64, 256, 0, stream>>>(aggB, W1t, b1, type_agg);
    k_final<<<B_, 128, 0, stream>>>(type_agg, nodes_fusion, Wt, W2, b2, Wc, bc,
                                    out, att_out);
}